// Round 7
// baseline (67.255 us; speedup 1.0000x reference)
//
#include <hip/hip_runtime.h>
#include <hip/hip_bf16.h>

#define BB 2
#define SS 128
#define HH 1024
#define AA 256
#define CC 14
#define R_TOT (BB*SS)   // 256 rows per net

typedef float  f32x4   __attribute__((ext_vector_type(4)));
typedef short  short8  __attribute__((ext_vector_type(8)));
typedef unsigned short ushort8v __attribute__((ext_vector_type(8)));

struct NetP { const float *W1,*b1,*W2,*b2,*s0W,*s0b,*s1W,*s1b; };
struct AllP { NetP n[3]; };

// ws BYTE offsets (all 256B-aligned)
#define OFF_S0   0           // [3][256][14] f32 = 43008
#define OFF_S1   43008
#define OFF_P1   86016       // [24][256][128] f32 = 3145728
#define OFF_HIDB 3231744     // [3][256][256] bf16 = 393216
#define OFF_OUT2 3624960     // [3][256][256] f32 = 786432
#define OFF_MEMB 4411392     // [256][1024] bf16 = 524288
#define OFF_W1T  4935680     // [3][256][1024] bf16 = 1572864
#define OFF_W2T  6508544     // [3][256][256] bf16 = 393216

__device__ __forceinline__ unsigned short f2b(float x) {
    return __bfloat16_as_ushort(__float2bfloat16(x));
}

// ---------------------------------------------------------------------------
// K0: convert mem -> bf16; transpose+convert W1,W2 -> [n][k] bf16.
// grid: [0,192) W1-tiles, [192,240) W2-tiles, [240,368) mem cvt. 256 thr.
// ---------------------------------------------------------------------------
__global__ __launch_bounds__(256)
void cvt_kernel(const float* __restrict__ mem, AllP P,
                unsigned short* __restrict__ membf,
                unsigned short* __restrict__ w1t,
                unsigned short* __restrict__ w2t)
{
    __shared__ float t[64][65];
    const int bx = blockIdx.x, tid = threadIdx.x;
    if (bx < 240) {
        const bool isW1 = bx < 192;
        const int idx  = isW1 ? bx : bx - 192;
        const int net  = isW1 ? (idx >> 6) : (idx >> 4);
        const int tile = isW1 ? (idx & 63) : (idx & 15);
        const int kt = tile >> 2, nt = tile & 3;
        const int k0 = kt*64, n0 = nt*64;
        const float* __restrict__ W = isW1 ? P.n[net].W1 : P.n[net].W2;
        #pragma unroll
        for (int p = 0; p < 4; ++p) {
            const int row = p*16 + (tid >> 4);
            const int col = (tid & 15) * 4;
            const float4 v = *(const float4*)(W + (size_t)(k0+row)*AA + n0 + col);
            t[row][col] = v.x; t[row][col+1] = v.y;
            t[row][col+2] = v.z; t[row][col+3] = v.w;
        }
        __syncthreads();
        unsigned short* __restrict__ out =
            isW1 ? (w1t + (size_t)net*AA*HH) : (w2t + (size_t)net*AA*AA);
        const int ldout = isW1 ? HH : AA;
        #pragma unroll
        for (int p = 0; p < 2; ++p) {
            const int nr = p*32 + (tid >> 3);
            const int kg = (tid & 7) * 8;
            ushort8v o;
            #pragma unroll
            for (int j = 0; j < 8; ++j) o[j] = f2b(t[kg + j][nr]);
            *(ushort8v*)(out + (size_t)(n0 + nr)*ldout + k0 + kg) = o;
        }
    } else {
        const int f = (bx - 240) * 2048 + tid * 8;
        const float4 v0 = *(const float4*)(mem + f);
        const float4 v1 = *(const float4*)(mem + f + 4);
        ushort8v o;
        o[0]=f2b(v0.x); o[1]=f2b(v0.y); o[2]=f2b(v0.z); o[3]=f2b(v0.w);
        o[4]=f2b(v1.x); o[5]=f2b(v1.y); o[6]=f2b(v1.z); o[7]=f2b(v1.w);
        *(ushort8v*)(membf + f) = o;
    }
}

// ---------------------------------------------------------------------------
// K1: GEMM1 partials, MFMA 16x16x32 bf16, no LDS.
// C_part = memb[256,K=256 chunk] @ W1T^T   per (net, nhalf, kchunk)
// grid = 3*2*4 = 24 blocks, 512 thr = 8 waves (4m x 2n), wave tile 64x64.
// A-frag: row=lane&15, k contiguous 8 @ (lane>>4)*8  (k-major memb)
// B-frag: col=lane&15, same k pattern (k-major w1t rows = W1 cols)
// D: col=lane&15, row=(lane>>4)*4+reg   [verified m89/m91]
// ---------------------------------------------------------------------------
__global__ __launch_bounds__(512)
void gemm1_kernel(const unsigned short* __restrict__ membf,
                  const unsigned short* __restrict__ w1t,
                  float* __restrict__ p1)
{
    const int net = blockIdx.x >> 3;
    const int nh  = (blockIdx.x >> 2) & 1;
    const int kc  = blockIdx.x & 3;
    const int tid = threadIdx.x, lane = tid & 63;
    const int wv  = tid >> 6;
    const int wm  = wv >> 1, wn = wv & 1;
    const int lrow = lane & 15;
    const int lk   = (lane >> 4) * 8;

    const unsigned short* __restrict__ Ab =
        membf + (size_t)(wm*64 + lrow)*HH + kc*256 + lk;
    const unsigned short* __restrict__ Bb =
        w1t + (size_t)net*AA*HH + (size_t)(nh*128 + wn*64 + lrow)*HH + kc*256 + lk;

    f32x4 acc[4][4];
    #pragma unroll
    for (int i = 0; i < 4; ++i)
        #pragma unroll
        for (int j = 0; j < 4; ++j) acc[i][j] = (f32x4){0.f,0.f,0.f,0.f};

    #pragma unroll 2
    for (int ks = 0; ks < 8; ++ks) {
        short8 a[4], b[4];
        #pragma unroll
        for (int f = 0; f < 4; ++f) {
            a[f] = *(const short8*)(Ab + (size_t)f*16*HH + ks*32);
            b[f] = *(const short8*)(Bb + (size_t)f*16*HH + ks*32);
        }
        #pragma unroll
        for (int fm = 0; fm < 4; ++fm)
            #pragma unroll
            for (int fn = 0; fn < 4; ++fn)
                acc[fm][fn] = __builtin_amdgcn_mfma_f32_16x16x32_bf16(
                    a[fm], b[fn], acc[fm][fn], 0, 0, 0);
    }

    float* __restrict__ Pt = p1 + (size_t)blockIdx.x * (256*128);
    const int drow = (lane >> 4) * 4;
    const int dcol = lane & 15;
    #pragma unroll
    for (int fm = 0; fm < 4; ++fm)
        #pragma unroll
        for (int fn = 0; fn < 4; ++fn) {
            const int m = wm*64 + fm*16 + drow;
            const int n = wn*64 + fn*16 + dcol;
            #pragma unroll
            for (int r = 0; r < 4; ++r)
                Pt[(size_t)(m + r)*128 + n] = acc[fm][fn][r];
        }
}

// ---------------------------------------------------------------------------
// K2: reduce split-K partials + b1 + relu -> hidb (bf16, k-major [m][256])
// grid = 3*2*16 = 96 blocks x 256 thr; thread: 8 consecutive n.
// ---------------------------------------------------------------------------
__global__ __launch_bounds__(256)
void reduce1_kernel(const float* __restrict__ p1, AllP P,
                    unsigned short* __restrict__ hidb)
{
    const int net = blockIdx.x >> 5;
    const int nh  = (blockIdx.x >> 4) & 1;
    const int mt  = blockIdx.x & 15;
    const int tid = threadIdx.x;
    const int row = mt*16 + (tid >> 4);
    const int n8  = (tid & 15) * 8;
    const float* __restrict__ base =
        p1 + (size_t)((net*2 + nh)*4) * (256*128) + (size_t)row*128 + n8;
    float s[8] = {0,0,0,0,0,0,0,0};
    #pragma unroll
    for (int kcv = 0; kcv < 4; ++kcv) {
        const float4 u0 = *(const float4*)(base + (size_t)kcv*(256*128));
        const float4 u1 = *(const float4*)(base + (size_t)kcv*(256*128) + 4);
        s[0]+=u0.x; s[1]+=u0.y; s[2]+=u0.z; s[3]+=u0.w;
        s[4]+=u1.x; s[5]+=u1.y; s[6]+=u1.z; s[7]+=u1.w;
    }
    const float* __restrict__ b1 = P.n[net].b1 + nh*128 + n8;
    ushort8v o;
    #pragma unroll
    for (int j = 0; j < 8; ++j) o[j] = f2b(fmaxf(s[j] + b1[j], 0.f));
    *(ushort8v*)(hidb + (size_t)net*AA*AA + (size_t)row*AA + nh*128 + n8) = o;
}

// ---------------------------------------------------------------------------
// K3: GEMM2 (full K=256) + b2 -> out2 fp32.  grid = 3*2 = 6 blocks, 512 thr.
// ---------------------------------------------------------------------------
__global__ __launch_bounds__(512)
void gemm2_kernel(const unsigned short* __restrict__ hidb,
                  const unsigned short* __restrict__ w2t, AllP P,
                  float* __restrict__ out2)
{
    const int net = blockIdx.x >> 1;
    const int nh  = blockIdx.x & 1;
    const int tid = threadIdx.x, lane = tid & 63;
    const int wv  = tid >> 6;
    const int wm  = wv >> 1, wn = wv & 1;
    const int lrow = lane & 15;
    const int lk   = (lane >> 4) * 8;

    const unsigned short* __restrict__ Ab =
        hidb + (size_t)net*AA*AA + (size_t)(wm*64 + lrow)*AA + lk;
    const unsigned short* __restrict__ Bb =
        w2t + (size_t)net*AA*AA + (size_t)(nh*128 + wn*64 + lrow)*AA + lk;

    f32x4 acc[4][4];
    #pragma unroll
    for (int i = 0; i < 4; ++i)
        #pragma unroll
        for (int j = 0; j < 4; ++j) acc[i][j] = (f32x4){0.f,0.f,0.f,0.f};

    #pragma unroll 2
    for (int ks = 0; ks < 8; ++ks) {
        short8 a[4], b[4];
        #pragma unroll
        for (int f = 0; f < 4; ++f) {
            a[f] = *(const short8*)(Ab + (size_t)f*16*AA + ks*32);
            b[f] = *(const short8*)(Bb + (size_t)f*16*AA + ks*32);
        }
        #pragma unroll
        for (int fm = 0; fm < 4; ++fm)
            #pragma unroll
            for (int fn = 0; fn < 4; ++fn)
                acc[fm][fn] = __builtin_amdgcn_mfma_f32_16x16x32_bf16(
                    a[fm], b[fn], acc[fm][fn], 0, 0, 0);
    }

    float* __restrict__ O = out2 + (size_t)net*AA*AA;
    const float* __restrict__ b2 = P.n[net].b2;
    const int drow = (lane >> 4) * 4;
    const int dcol = lane & 15;
    #pragma unroll
    for (int fm = 0; fm < 4; ++fm)
        #pragma unroll
        for (int fn = 0; fn < 4; ++fn) {
            const int m = wm*64 + fm*16 + drow;
            const int n = nh*128 + wn*64 + fn*16 + dcol;
            const float bv = b2[n];
            #pragma unroll
            for (int r = 0; r < 4; ++r)
                O[(size_t)(m + r)*AA + n] = acc[fm][fn][r] + bv;
        }
}

// ---------------------------------------------------------------------------
// K4: projections to C=14 (fp32). grid = 3*16 = 48 blocks x 512 thr.
// Stage out2 rows transposed in LDS [k][m] -> conflict-free broadcast dots.
// ---------------------------------------------------------------------------
__global__ __launch_bounds__(512)
void proj_kernel(const float* __restrict__ out2, AllP P,
                 float* __restrict__ s0o, float* __restrict__ s1o)
{
    const int net  = blockIdx.x >> 4;
    const int rt   = blockIdx.x & 15;
    const int row0 = rt * 16;
    const int tid  = threadIdx.x;
    __shared__ float ldsT[256][16];
    #pragma unroll
    for (int u = 0; u < 2; ++u) {
        const int idx = tid*8 + u*4;
        const int row = idx >> 8;
        const int k   = idx & 255;
        const float4 v = *(const float4*)(out2 + (size_t)net*AA*AA
                                          + (size_t)(row0+row)*AA + k);
        ldsT[k][row] = v.x; ldsT[k+1][row] = v.y;
        ldsT[k+2][row] = v.z; ldsT[k+3][row] = v.w;
    }
    __syncthreads();
    if (tid < 448) {
        const int which = (tid >= 224) ? 1 : 0;
        const int rem = tid - which*224;
        const int r = rem / CC, c = rem % CC;
        const NetP p = P.n[net];
        const float* __restrict__ W = which ? p.s1W : p.s0W;
        float s = (which ? p.s1b : p.s0b)[c];
        #pragma unroll 4
        for (int k = 0; k < AA; ++k)
            s = fmaf(ldsT[k][r], W[(size_t)k*CC + c], s);
        (which ? s1o : s0o)[((size_t)net*R_TOT + row0 + r)*CC + c] = s;
    }
}

// ---------------------------------------------------------------------------
// K5: fused prefix + output fill (unchanged — proven).
// ---------------------------------------------------------------------------
__global__ __launch_bounds__(512)
void final_kernel(const float* __restrict__ s0w, const float* __restrict__ s1w,
                  const float* __restrict__ uni, float* __restrict__ out)
{
    const int bi = blockIdx.x;        // b*S + i
    const int b = bi >> 7, i = bi & (SS-1);
    const int tid = threadIdx.x;
    const int lane = tid & 63;
    const int k    = tid & 127;
    const int wv2  = (tid >> 6) & 1;
    const int slot = tid >> 7;

    __shared__ float E[SS*CC];
    __shared__ float Qe[SS*CC];
    __shared__ float red[4][4][2];
    __shared__ float mnL[CC], sh1L[CC], uniL[CC];

    if (tid < CC) {
        sh1L[tid] = s1w[(size_t)bi*CC + tid];
        uniL[tid] = uni[tid];
    }

    const float* __restrict__ sm0b = s0w + (size_t)(2*R_TOT + b*SS)*CC;
    const float* __restrict__ sm1b = s1w + (size_t)(2*R_TOT + b*SS)*CC;

    for (int pass = 0; pass < 4; ++pass) {
        const int c = pass*4 + slot;
        float x0 = 0.f, x1 = 0.f, e = 0.f, q = 0.f;
        if (c < CC) {
            x0 = sm0b[(size_t)k*CC + c];
            x1 = sm1b[(size_t)k*CC + c];
            float m = x0;
            #pragma unroll
            for (int off = 32; off >= 1; off >>= 1) m = fmaxf(m, __shfl_xor(m, off));
            float ss = x1;
            #pragma unroll
            for (int off = 32; off >= 1; off >>= 1) ss += __shfl_xor(ss, off);
            if (lane == 0) { red[0][slot][wv2] = m; red[1][slot][wv2] = ss; }
        }
        __syncthreads();
        if (c < CC) {
            const float M = fmaxf(red[0][slot][0], red[0][slot][1]);
            e = __expf(x0 - M);
            q = e * x1;
            #pragma unroll
            for (int off = 1; off <= 32; off <<= 1) {
                const float te = __shfl_up(e, off);
                const float tq = __shfl_up(q, off);
                if (lane >= off) { e += te; q += tq; }
            }
            if (lane == 63) { red[2][slot][wv2] = e; red[3][slot][wv2] = q; }
        }
        __syncthreads();
        if (c < CC) {
            if (wv2 == 1) { e += red[2][slot][0]; q += red[3][slot][0]; }
            E [k*CC + c] = e;
            Qe[k*CC + c] = q;
            if (k == 0) mnL[c] = (red[1][slot][0] + red[1][slot][1]) * (1.f/SS);
        }
        __syncthreads();
    }

    const float* __restrict__ st1 = s1w + (size_t)(R_TOT + b*SS)*CC;
    float* __restrict__ o = out + (size_t)bi*SS*CC;
    if (tid < 448) {
        const int e0 = tid * 4;
        float v[4];
        #pragma unroll
        for (int u = 0; u < 4; ++u) {
            const int idx = e0 + u;
            const int j = idx / CC, c = idx - j*CC;
            float add;
            if (i <= j) {
                const float Ei = (i > 0) ? E [(i-1)*CC + c] : 0.f;
                const float Qi = (i > 0) ? Qe[(i-1)*CC + c] : 0.f;
                add = (Qe[j*CC + c] - Qi) / (E[j*CC + c] - Ei);
            } else {
                add = mnL[c];
            }
            v[u] = sh1L[c] + st1[idx] + uniL[c] + add;
        }
        *(float4*)&o[e0] = make_float4(v[0], v[1], v[2], v[3]);
    }
}

extern "C" void kernel_launch(void* const* d_in, const int* in_sizes, int n_in,
                              void* d_out, int out_size, void* d_ws, size_t ws_size,
                              hipStream_t stream)
{
    const float* mem = (const float*)d_in[0];
    AllP P;
    for (int n = 0; n < 3; ++n) {
        const int base = 1 + 8*n;
        P.n[n].W1  = (const float*)d_in[base+0];
        P.n[n].b1  = (const float*)d_in[base+1];
        P.n[n].W2  = (const float*)d_in[base+2];
        P.n[n].b2  = (const float*)d_in[base+3];
        P.n[n].s0W = (const float*)d_in[base+4];
        P.n[n].s0b = (const float*)d_in[base+5];
        P.n[n].s1W = (const float*)d_in[base+6];
        P.n[n].s1b = (const float*)d_in[base+7];
    }
    const float* uni = (const float*)d_in[25];
    char* wsb = (char*)d_ws;
    float* s0   = (float*)(wsb + OFF_S0);
    float* s1   = (float*)(wsb + OFF_S1);
    float* p1   = (float*)(wsb + OFF_P1);
    float* out2 = (float*)(wsb + OFF_OUT2);
    unsigned short* hidb  = (unsigned short*)(wsb + OFF_HIDB);
    unsigned short* membf = (unsigned short*)(wsb + OFF_MEMB);
    unsigned short* w1t   = (unsigned short*)(wsb + OFF_W1T);
    unsigned short* w2t   = (unsigned short*)(wsb + OFF_W2T);
    float* out = (float*)d_out;

    hipLaunchKernelGGL(cvt_kernel,     dim3(368), dim3(256), 0, stream, mem, P, membf, w1t, w2t);
    hipLaunchKernelGGL(gemm1_kernel,   dim3(24),  dim3(512), 0, stream, membf, w1t, p1);
    hipLaunchKernelGGL(reduce1_kernel, dim3(96),  dim3(256), 0, stream, p1, P, hidb);
    hipLaunchKernelGGL(gemm2_kernel,   dim3(6),   dim3(512), 0, stream, hidb, w2t, P, out2);
    hipLaunchKernelGGL(proj_kernel,    dim3(48),  dim3(512), 0, stream, out2, P, s0, s1);
    hipLaunchKernelGGL(final_kernel,   dim3(BB*SS), dim3(512), 0, stream, s0, s1, uni, out);
}

// Round 8
// 59.242 us; speedup vs baseline: 1.1353x; 1.1353x over previous
//
#include <hip/hip_runtime.h>
#include <hip/hip_bf16.h>

#define BB 2
#define SS 128
#define HH 1024
#define AA 256
#define CC 14
#define R_TOT (BB*SS)   // 256 rows per net

typedef float  f32x4   __attribute__((ext_vector_type(4)));
typedef short  short8  __attribute__((ext_vector_type(8)));
typedef unsigned short ushort8v __attribute__((ext_vector_type(8)));

struct NetP { const float *W1,*b1,*W2,*b2,*s0W,*s0b,*s1W,*s1b; };
struct AllP { NetP n[3]; };

// ws BYTE offsets (256B aligned)
#define OFF_S0   0           // [3][256][14] f32 = 43008
#define OFF_S1   43008       // 43008
#define OFF_OUT2 86016       // [3][256][256] f32 = 786432
#define OFF_HIDB 872448      // [3][256][256] bf16 = 393216
#define OFF_MEMB 1265664     // [256][1024] bf16 = 524288
#define OFF_W1T  1789952     // [3][256][1024] bf16 = 1572864
#define OFF_W2T  3362816     // [3][256][256] bf16 = 393216

__device__ __forceinline__ unsigned short f2b(float x) {
    return __bfloat16_as_ushort(__float2bfloat16(x));
}

// ---------------------------------------------------------------------------
// K0: convert mem -> bf16; transpose+convert W1,W2 -> [n][k] bf16.
// grid: [0,192) W1-tiles, [192,240) W2-tiles, [240,368) mem cvt. 256 thr.
// (verbatim from R7 — validated)
// ---------------------------------------------------------------------------
__global__ __launch_bounds__(256)
void cvt_kernel(const float* __restrict__ mem, AllP P,
                unsigned short* __restrict__ membf,
                unsigned short* __restrict__ w1t,
                unsigned short* __restrict__ w2t)
{
    __shared__ float t[64][65];
    const int bx = blockIdx.x, tid = threadIdx.x;
    if (bx < 240) {
        const bool isW1 = bx < 192;
        const int idx  = isW1 ? bx : bx - 192;
        const int net  = isW1 ? (idx >> 6) : (idx >> 4);
        const int tile = isW1 ? (idx & 63) : (idx & 15);
        const int kt = tile >> 2, nt = tile & 3;
        const int k0 = kt*64, n0 = nt*64;
        const float* __restrict__ W = isW1 ? P.n[net].W1 : P.n[net].W2;
        #pragma unroll
        for (int p = 0; p < 4; ++p) {
            const int row = p*16 + (tid >> 4);
            const int col = (tid & 15) * 4;
            const float4 v = *(const float4*)(W + (size_t)(k0+row)*AA + n0 + col);
            t[row][col] = v.x; t[row][col+1] = v.y;
            t[row][col+2] = v.z; t[row][col+3] = v.w;
        }
        __syncthreads();
        unsigned short* __restrict__ out =
            isW1 ? (w1t + (size_t)net*AA*HH) : (w2t + (size_t)net*AA*AA);
        const int ldout = isW1 ? HH : AA;
        #pragma unroll
        for (int p = 0; p < 2; ++p) {
            const int nr = p*32 + (tid >> 3);
            const int kg = (tid & 7) * 8;
            ushort8v o;
            #pragma unroll
            for (int j = 0; j < 8; ++j) o[j] = f2b(t[kg + j][nr]);
            *(ushort8v*)(out + (size_t)(n0 + nr)*ldout + k0 + kg) = o;
        }
    } else {
        const int f = (bx - 240) * 2048 + tid * 8;
        const float4 v0 = *(const float4*)(mem + f);
        const float4 v1 = *(const float4*)(mem + f + 4);
        ushort8v o;
        o[0]=f2b(v0.x); o[1]=f2b(v0.y); o[2]=f2b(v0.z); o[3]=f2b(v0.w);
        o[4]=f2b(v1.x); o[5]=f2b(v1.y); o[6]=f2b(v1.z); o[7]=f2b(v1.w);
        *(ushort8v*)(membf + f) = o;
    }
}

// ---------------------------------------------------------------------------
// K1: GEMM1 full-K + b1 + relu -> hidb bf16.  hid = relu(mem@W1+b1)
// grid = 48: mt(4 of 64 rows) x [net(3) x ns(4 of 64 cols)].  256 thr = 4 waves
// wave tile 32x32 (2x2 frags of 16x16), K=1024 in 32 steps.
// Fragment layouts validated in R7 (absmax 7.8e-3).
// ---------------------------------------------------------------------------
__global__ __launch_bounds__(256)
void gemm1_kernel(const unsigned short* __restrict__ membf,
                  const unsigned short* __restrict__ w1t, AllP P,
                  unsigned short* __restrict__ hidb)
{
    const int gt = blockIdx.x >> 2;       // 0..11
    const int mt = blockIdx.x & 3;        // 0..3
    const int net = gt >> 2;              // 0..2
    const int ns  = gt & 3;               // 0..3
    const int tid = threadIdx.x, lane = tid & 63;
    const int wv  = tid >> 6;             // 0..3
    const int wm  = wv >> 1, wn = wv & 1;
    const int lrow = lane & 15;
    const int lk   = (lane >> 4) * 8;

    const unsigned short* __restrict__ Ab =
        membf + (size_t)(mt*64 + wm*32 + lrow)*HH + lk;
    const unsigned short* __restrict__ Bb =
        w1t + (size_t)net*AA*HH + (size_t)(ns*64 + wn*32 + lrow)*HH + lk;

    f32x4 acc[2][2];
    #pragma unroll
    for (int i = 0; i < 2; ++i)
        #pragma unroll
        for (int j = 0; j < 2; ++j) acc[i][j] = (f32x4){0.f,0.f,0.f,0.f};

    #pragma unroll 4
    for (int ks = 0; ks < 32; ++ks) {
        short8 a[2], b[2];
        #pragma unroll
        for (int f = 0; f < 2; ++f) {
            a[f] = *(const short8*)(Ab + (size_t)f*16*HH + ks*32);
            b[f] = *(const short8*)(Bb + (size_t)f*16*HH + ks*32);
        }
        #pragma unroll
        for (int fm = 0; fm < 2; ++fm)
            #pragma unroll
            for (int fn = 0; fn < 2; ++fn)
                acc[fm][fn] = __builtin_amdgcn_mfma_f32_16x16x32_bf16(
                    a[fm], b[fn], acc[fm][fn], 0, 0, 0);
    }

    const float* __restrict__ b1 = P.n[net].b1;
    const int drow = (lane >> 4) * 4;
    const int dcol = lane & 15;
    unsigned short* __restrict__ H = hidb + (size_t)net*AA*AA;
    #pragma unroll
    for (int fm = 0; fm < 2; ++fm)
        #pragma unroll
        for (int fn = 0; fn < 2; ++fn) {
            const int m = mt*64 + wm*32 + fm*16 + drow;
            const int n = ns*64 + wn*32 + fn*16 + dcol;
            const float bv = b1[n];
            #pragma unroll
            for (int r = 0; r < 4; ++r)
                H[(size_t)(m + r)*AA + n] = f2b(fmaxf(acc[fm][fn][r] + bv, 0.f));
        }
}

// ---------------------------------------------------------------------------
// K2: GEMM2 full-K + b2 -> out2 f32.  out2 = hid@W2+b2
// grid = 24: net(3) x mt(8 of 32 rows).  512 thr = 8 waves (2m x 4n),
// wave tile 16m x 64n (1x4 frags), K=256 in 8 steps.
// ---------------------------------------------------------------------------
__global__ __launch_bounds__(512)
void gemm2_kernel(const unsigned short* __restrict__ hidb,
                  const unsigned short* __restrict__ w2t, AllP P,
                  float* __restrict__ out2)
{
    const int net = blockIdx.x >> 3;
    const int mt  = blockIdx.x & 7;
    const int row0 = mt * 32;
    const int tid = threadIdx.x, lane = tid & 63;
    const int wv  = tid >> 6;             // 0..7
    const int wm  = wv >> 2, wn = wv & 3;
    const int lrow = lane & 15;
    const int lk   = (lane >> 4) * 8;

    const unsigned short* __restrict__ Ab =
        hidb + (size_t)net*AA*AA + (size_t)(row0 + wm*16 + lrow)*AA + lk;
    const unsigned short* __restrict__ Bb =
        w2t + (size_t)net*AA*AA + (size_t)(wn*64 + lrow)*AA + lk;

    f32x4 acc[4];
    #pragma unroll
    for (int j = 0; j < 4; ++j) acc[j] = (f32x4){0.f,0.f,0.f,0.f};

    #pragma unroll 2
    for (int ks = 0; ks < 8; ++ks) {
        short8 a, b[4];
        a = *(const short8*)(Ab + ks*32);
        #pragma unroll
        for (int f = 0; f < 4; ++f)
            b[f] = *(const short8*)(Bb + (size_t)f*16*AA + ks*32);
        #pragma unroll
        for (int fn = 0; fn < 4; ++fn)
            acc[fn] = __builtin_amdgcn_mfma_f32_16x16x32_bf16(
                a, b[fn], acc[fn], 0, 0, 0);
    }

    float* __restrict__ O = out2 + (size_t)net*AA*AA;
    const float* __restrict__ b2 = P.n[net].b2;
    const int drow = (lane >> 4) * 4;
    const int dcol = lane & 15;
    #pragma unroll
    for (int fn = 0; fn < 4; ++fn) {
        const int m = row0 + wm*16 + drow;
        const int n = wn*64 + fn*16 + dcol;
        const float bv = b2[n];
        #pragma unroll
        for (int r = 0; r < 4; ++r)
            O[(size_t)(m + r)*AA + n] = acc[fn][r] + bv;
    }
}

// ---------------------------------------------------------------------------
// K3: projections to C=14 (fp32 VALU, reads L1/L2-resident out2 and W).
// grid = 96: net(3) x rowtile(32 of 8 rows).  256 thr, 224 active.
// ---------------------------------------------------------------------------
__global__ __launch_bounds__(256)
void proj_kernel(const float* __restrict__ out2, AllP P,
                 float* __restrict__ s0o, float* __restrict__ s1o)
{
    const int net  = blockIdx.x >> 5;
    const int rt   = blockIdx.x & 31;
    const int row0 = rt * 8;
    const int tid  = threadIdx.x;
    if (tid >= 224) return;
    const int which = (tid >= 112) ? 1 : 0;
    const int rem   = tid - which*112;
    const int r = rem / CC, c = rem % CC;
    const NetP p = P.n[net];
    const float* __restrict__ W = which ? p.s1W : p.s0W;
    const float* __restrict__ x = out2 + (size_t)net*AA*AA + (size_t)(row0 + r)*AA;
    float s0a = 0.f, s1a = 0.f, s2a = 0.f, s3a = 0.f;
    #pragma unroll 4
    for (int k = 0; k < 64; ++k) {
        s0a = fmaf(x[k],       W[(size_t)k*CC + c],        s0a);
        s1a = fmaf(x[k + 64],  W[(size_t)(k+64)*CC + c],   s1a);
        s2a = fmaf(x[k + 128], W[(size_t)(k+128)*CC + c],  s2a);
        s3a = fmaf(x[k + 192], W[(size_t)(k+192)*CC + c],  s3a);
    }
    const float s = (s0a + s1a) + (s2a + s3a) + (which ? p.s1b : p.s0b)[c];
    (which ? s1o : s0o)[((size_t)net*R_TOT + row0 + r)*CC + c] = s;
}

// ---------------------------------------------------------------------------
// K4: fused prefix + output fill (unchanged — proven).
// ---------------------------------------------------------------------------
__global__ __launch_bounds__(512)
void final_kernel(const float* __restrict__ s0w, const float* __restrict__ s1w,
                  const float* __restrict__ uni, float* __restrict__ out)
{
    const int bi = blockIdx.x;        // b*S + i
    const int b = bi >> 7, i = bi & (SS-1);
    const int tid = threadIdx.x;
    const int lane = tid & 63;
    const int k    = tid & 127;
    const int wv2  = (tid >> 6) & 1;
    const int slot = tid >> 7;

    __shared__ float E[SS*CC];
    __shared__ float Qe[SS*CC];
    __shared__ float red[4][4][2];
    __shared__ float mnL[CC], sh1L[CC], uniL[CC];

    if (tid < CC) {
        sh1L[tid] = s1w[(size_t)bi*CC + tid];
        uniL[tid] = uni[tid];
    }

    const float* __restrict__ sm0b = s0w + (size_t)(2*R_TOT + b*SS)*CC;
    const float* __restrict__ sm1b = s1w + (size_t)(2*R_TOT + b*SS)*CC;

    for (int pass = 0; pass < 4; ++pass) {
        const int c = pass*4 + slot;
        float x0 = 0.f, x1 = 0.f, e = 0.f, q = 0.f;
        if (c < CC) {
            x0 = sm0b[(size_t)k*CC + c];
            x1 = sm1b[(size_t)k*CC + c];
            float m = x0;
            #pragma unroll
            for (int off = 32; off >= 1; off >>= 1) m = fmaxf(m, __shfl_xor(m, off));
            float ss = x1;
            #pragma unroll
            for (int off = 32; off >= 1; off >>= 1) ss += __shfl_xor(ss, off);
            if (lane == 0) { red[0][slot][wv2] = m; red[1][slot][wv2] = ss; }
        }
        __syncthreads();
        if (c < CC) {
            const float M = fmaxf(red[0][slot][0], red[0][slot][1]);
            e = __expf(x0 - M);
            q = e * x1;
            #pragma unroll
            for (int off = 1; off <= 32; off <<= 1) {
                const float te = __shfl_up(e, off);
                const float tq = __shfl_up(q, off);
                if (lane >= off) { e += te; q += tq; }
            }
            if (lane == 63) { red[2][slot][wv2] = e; red[3][slot][wv2] = q; }
        }
        __syncthreads();
        if (c < CC) {
            if (wv2 == 1) { e += red[2][slot][0]; q += red[3][slot][0]; }
            E [k*CC + c] = e;
            Qe[k*CC + c] = q;
            if (k == 0) mnL[c] = (red[1][slot][0] + red[1][slot][1]) * (1.f/SS);
        }
        __syncthreads();
    }

    const float* __restrict__ st1 = s1w + (size_t)(R_TOT + b*SS)*CC;
    float* __restrict__ o = out + (size_t)bi*SS*CC;
    if (tid < 448) {
        const int e0 = tid * 4;
        float v[4];
        #pragma unroll
        for (int u = 0; u < 4; ++u) {
            const int idx = e0 + u;
            const int j = idx / CC, c = idx - j*CC;
            float add;
            if (i <= j) {
                const float Ei = (i > 0) ? E [(i-1)*CC + c] : 0.f;
                const float Qi = (i > 0) ? Qe[(i-1)*CC + c] : 0.f;
                add = (Qe[j*CC + c] - Qi) / (E[j*CC + c] - Ei);
            } else {
                add = mnL[c];
            }
            v[u] = sh1L[c] + st1[idx] + uniL[c] + add;
        }
        *(float4*)&o[e0] = make_float4(v[0], v[1], v[2], v[3]);
    }
}

extern "C" void kernel_launch(void* const* d_in, const int* in_sizes, int n_in,
                              void* d_out, int out_size, void* d_ws, size_t ws_size,
                              hipStream_t stream)
{
    const float* mem = (const float*)d_in[0];
    AllP P;
    for (int n = 0; n < 3; ++n) {
        const int base = 1 + 8*n;
        P.n[n].W1  = (const float*)d_in[base+0];
        P.n[n].b1  = (const float*)d_in[base+1];
        P.n[n].W2  = (const float*)d_in[base+2];
        P.n[n].b2  = (const float*)d_in[base+3];
        P.n[n].s0W = (const float*)d_in[base+4];
        P.n[n].s0b = (const float*)d_in[base+5];
        P.n[n].s1W = (const float*)d_in[base+6];
        P.n[n].s1b = (const float*)d_in[base+7];
    }
    const float* uni = (const float*)d_in[25];
    char* wsb = (char*)d_ws;
    float* s0   = (float*)(wsb + OFF_S0);
    float* s1   = (float*)(wsb + OFF_S1);
    float* out2 = (float*)(wsb + OFF_OUT2);
    unsigned short* hidb  = (unsigned short*)(wsb + OFF_HIDB);
    unsigned short* membf = (unsigned short*)(wsb + OFF_MEMB);
    unsigned short* w1t   = (unsigned short*)(wsb + OFF_W1T);
    unsigned short* w2t   = (unsigned short*)(wsb + OFF_W2T);
    float* out = (float*)d_out;

    hipLaunchKernelGGL(cvt_kernel,   dim3(368), dim3(256), 0, stream, mem, P, membf, w1t, w2t);
    hipLaunchKernelGGL(gemm1_kernel, dim3(48),  dim3(256), 0, stream, membf, w1t, P, hidb);
    hipLaunchKernelGGL(gemm2_kernel, dim3(24),  dim3(512), 0, stream, hidb, w2t, P, out2);
    hipLaunchKernelGGL(proj_kernel,  dim3(96),  dim3(256), 0, stream, out2, P, s0, s1);
    hipLaunchKernelGGL(final_kernel, dim3(BB*SS), dim3(512), 0, stream, s0, s1, uni, out);
}

// Round 9
// 37.747 us; speedup vs baseline: 1.7817x; 1.5694x over previous
//
#include <hip/hip_runtime.h>
#include <hip/hip_bf16.h>

#define BB 2
#define SS 128
#define HH 1024
#define AA 256
#define CC 14
#define R_TOT (BB*SS)   // 256 rows per net

typedef float f32x4 __attribute__((ext_vector_type(4)));
typedef unsigned short ushort8v __attribute__((ext_vector_type(8)));

struct NetP { const float *W1,*b1,*W2,*b2,*s0W,*s0b,*s1W,*s1b; };
struct AllP { NetP n[3]; };

// ws float offsets
#define S0_OFF 0                         // [3][256][14]
#define S1_OFF (3*R_TOT*CC)
// bf16 weight copies (ushort), [k][n] layout, byte offsets
#define W1B_OFF_BYTES (64*1024)                      // 3*1024*256 ushort = 1.5 MB
#define W2B_OFF_BYTES (W1B_OFF_BYTES + 3*HH*AA*2)    // 3*256*256 ushort = 384 KB

#define W1_ELEMS (3*HH*AA)   // 786432
#define W2_ELEMS (3*AA*AA)   // 196608

__device__ __forceinline__ float bf16u_to_f(unsigned short u) {
    return __uint_as_float(((unsigned)u) << 16);
}
__device__ __forceinline__ unsigned short f2b(float x) {
    return __bfloat16_as_ushort(__float2bfloat16(x));
}

// ---------------------------------------------------------------------------
// K0: convert W1, W2 (fp32) -> bf16 (RNE) into ws. (verbatim R6 — measured ~2us)
// ---------------------------------------------------------------------------
__global__ __launch_bounds__(512)
void cvt_kernel(AllP P, unsigned short* __restrict__ w1b,
                unsigned short* __restrict__ w2b)
{
    const int idx0 = (blockIdx.x * 512 + threadIdx.x) * 4;
    #pragma unroll
    for (int u = 0; u < 4; ++u) {
        const int idx = idx0 + u;
        if (idx < W1_ELEMS) {
            const int net = idx / (HH*AA), r = idx % (HH*AA);
            w1b[idx] = f2b(P.n[net].W1[r]);
        } else if (idx < W1_ELEMS + W2_ELEMS) {
            const int j = idx - W1_ELEMS;
            const int net = j / (AA*AA), r = j % (AA*AA);
            w2b[j] = f2b(P.n[net].W2[r]);
        }
    }
}

// ---------------------------------------------------------------------------
// K_A: fully fused MLP per 4-row tile, bf16 weights, HALVED load count:
// each lane loads ushort8 (16B) = 8 cols of one k-row; half-wave koff=lane>>5
// covers k-parity; cross-half shfl_xor(32) reduce. Layer-1: 64 loads/wave
// (was 128); layer-2: 16 (was 32). fp32 accumulate throughout.
// grid = net(3) * rowtile(64 of 4 rows) = 192 blocks, 512 thr = 8 waves.
// ---------------------------------------------------------------------------
__global__ __launch_bounds__(512)
void mlp_fused(const float* __restrict__ mem, AllP P,
               const unsigned short* __restrict__ w1b,
               const unsigned short* __restrict__ w2b,
               float* __restrict__ s0o, float* __restrict__ s1o)
{
    const int bx   = blockIdx.x;
    const int net  = bx >> 6;           // 0..2
    const int rt   = bx & 63;           // 0..63
    const int row0 = rt * 4;
    const NetP p  = P.n[net];
    const int tid  = threadIdx.x;
    const int lane = tid & 63;
    const int wv   = __builtin_amdgcn_readfirstlane(tid >> 6); // 0..7
    const int koff = lane >> 5;         // 0/1: k parity handled by this half
    const int colb = (lane & 31) * 8;   // 8-col group base

    __shared__ float part[8][4][AA];    // 32 KB
    __shared__ float hidL[4][AA];       // 4 KB
    __shared__ float outL[4][AA];       // 4 KB
    __shared__ float pp[112][4];        // 1.75 KB

    // ================= layer 1 (K=1024, 128/wave, 64 iters) =================
    {
        const int k0 = wv * 128;
        const unsigned short* __restrict__ W1p =
            w1b + (size_t)net*HH*AA + (size_t)(k0 + koff)*AA + colb;
        const float* __restrict__ m0 = mem + (size_t)(row0+0)*HH + k0;
        const float* __restrict__ m1 = mem + (size_t)(row0+1)*HH + k0;
        const float* __restrict__ m2 = mem + (size_t)(row0+2)*HH + k0;
        const float* __restrict__ m3 = mem + (size_t)(row0+3)*HH + k0;
        float a0[8] = {0,0,0,0,0,0,0,0}, a1[8] = {0,0,0,0,0,0,0,0};
        float a2[8] = {0,0,0,0,0,0,0,0}, a3[8] = {0,0,0,0,0,0,0,0};
        #pragma unroll 8
        for (int it = 0; it < 64; ++it) {
            const ushort8v wu = *(const ushort8v*)(W1p + (size_t)(2*it)*AA);
            const float2 q0 = *(const float2*)(m0 + 2*it);   // uniform -> s_load
            const float2 q1 = *(const float2*)(m1 + 2*it);
            const float2 q2 = *(const float2*)(m2 + 2*it);
            const float2 q3 = *(const float2*)(m3 + 2*it);
            const float v0 = koff ? q0.y : q0.x;
            const float v1 = koff ? q1.y : q1.x;
            const float v2 = koff ? q2.y : q2.x;
            const float v3 = koff ? q3.y : q3.x;
            #pragma unroll
            for (int j = 0; j < 8; ++j) {
                const float w = bf16u_to_f(wu[j]);
                a0[j] = fmaf(v0, w, a0[j]);
                a1[j] = fmaf(v1, w, a1[j]);
                a2[j] = fmaf(v2, w, a2[j]);
                a3[j] = fmaf(v3, w, a3[j]);
            }
        }
        #pragma unroll
        for (int j = 0; j < 8; ++j) {
            a0[j] += __shfl_xor(a0[j], 32);
            a1[j] += __shfl_xor(a1[j], 32);
            a2[j] += __shfl_xor(a2[j], 32);
            a3[j] += __shfl_xor(a3[j], 32);
        }
        if (lane < 32) {
            *(f32x4*)&part[wv][0][colb]   = (f32x4){a0[0],a0[1],a0[2],a0[3]};
            *(f32x4*)&part[wv][0][colb+4] = (f32x4){a0[4],a0[5],a0[6],a0[7]};
            *(f32x4*)&part[wv][1][colb]   = (f32x4){a1[0],a1[1],a1[2],a1[3]};
            *(f32x4*)&part[wv][1][colb+4] = (f32x4){a1[4],a1[5],a1[6],a1[7]};
            *(f32x4*)&part[wv][2][colb]   = (f32x4){a2[0],a2[1],a2[2],a2[3]};
            *(f32x4*)&part[wv][2][colb+4] = (f32x4){a2[4],a2[5],a2[6],a2[7]};
            *(f32x4*)&part[wv][3][colb]   = (f32x4){a3[0],a3[1],a3[2],a3[3]};
            *(f32x4*)&part[wv][3][colb+4] = (f32x4){a3[4],a3[5],a3[6],a3[7]};
        }
    }
    __syncthreads();
    for (int i = tid; i < 4*AA; i += 512) {
        const int r = i >> 8, u = i & (AA-1);
        float s = p.b1[u];
        #pragma unroll
        for (int w = 0; w < 8; ++w) s += part[w][r][u];
        hidL[r][u] = fmaxf(s, 0.f);
    }
    __syncthreads();

    // ================= layer 2 (K=256, 32/wave, 16 iters) =================
    {
        const int k0 = wv * 32;
        const unsigned short* __restrict__ W2p =
            w2b + (size_t)net*AA*AA + (size_t)(k0 + koff)*AA + colb;
        float a0[8] = {0,0,0,0,0,0,0,0}, a1[8] = {0,0,0,0,0,0,0,0};
        float a2[8] = {0,0,0,0,0,0,0,0}, a3[8] = {0,0,0,0,0,0,0,0};
        #pragma unroll 8
        for (int it = 0; it < 16; ++it) {
            const ushort8v wu = *(const ushort8v*)(W2p + (size_t)(2*it)*AA);
            const int kk = k0 + 2*it + koff;
            const float v0 = hidL[0][kk];   // 2-addr LDS broadcast
            const float v1 = hidL[1][kk];
            const float v2 = hidL[2][kk];
            const float v3 = hidL[3][kk];
            #pragma unroll
            for (int j = 0; j < 8; ++j) {
                const float w = bf16u_to_f(wu[j]);
                a0[j] = fmaf(v0, w, a0[j]);
                a1[j] = fmaf(v1, w, a1[j]);
                a2[j] = fmaf(v2, w, a2[j]);
                a3[j] = fmaf(v3, w, a3[j]);
            }
        }
        #pragma unroll
        for (int j = 0; j < 8; ++j) {
            a0[j] += __shfl_xor(a0[j], 32);
            a1[j] += __shfl_xor(a1[j], 32);
            a2[j] += __shfl_xor(a2[j], 32);
            a3[j] += __shfl_xor(a3[j], 32);
        }
        __syncthreads();   // all layer-1 part reads done before overwrite
        if (lane < 32) {
            *(f32x4*)&part[wv][0][colb]   = (f32x4){a0[0],a0[1],a0[2],a0[3]};
            *(f32x4*)&part[wv][0][colb+4] = (f32x4){a0[4],a0[5],a0[6],a0[7]};
            *(f32x4*)&part[wv][1][colb]   = (f32x4){a1[0],a1[1],a1[2],a1[3]};
            *(f32x4*)&part[wv][1][colb+4] = (f32x4){a1[4],a1[5],a1[6],a1[7]};
            *(f32x4*)&part[wv][2][colb]   = (f32x4){a2[0],a2[1],a2[2],a2[3]};
            *(f32x4*)&part[wv][2][colb+4] = (f32x4){a2[4],a2[5],a2[6],a2[7]};
            *(f32x4*)&part[wv][3][colb]   = (f32x4){a3[0],a3[1],a3[2],a3[3]};
            *(f32x4*)&part[wv][3][colb+4] = (f32x4){a3[4],a3[5],a3[6],a3[7]};
        }
    }
    __syncthreads();
    for (int i = tid; i < 4*AA; i += 512) {
        const int r = i >> 8, u = i & (AA-1);
        float s = p.b2[u];
        #pragma unroll
        for (int w = 0; w < 8; ++w) s += part[w][r][u];
        outL[r][u] = s;
    }
    __syncthreads();

    // ================= projections to C=14 (verbatim R5/R6) =================
    if (tid < 448) {
        const int task = tid >> 2, kc = tid & 3;
        const int which = (task >= 56) ? 1 : 0;
        const int rem2  = task - which*56;
        const int rr = rem2 / CC, c = rem2 % CC;
        const float* __restrict__ W = which ? p.s1W : p.s0W;
        float s = 0.f;
        #pragma unroll 4
        for (int k = kc*64; k < kc*64 + 64; ++k)
            s = fmaf(outL[rr][k], W[(size_t)k*CC + c], s);
        pp[task][kc] = s;
    }
    __syncthreads();
    if (tid < 112) {
        const int which = (tid >= 56) ? 1 : 0;
        const int rem2  = tid - which*56;
        const int rr = rem2 / CC, c = rem2 % CC;
        const float s = pp[tid][0]+pp[tid][1]+pp[tid][2]+pp[tid][3]
                      + (which ? p.s1b : p.s0b)[c];
        (which ? s1o : s0o)[((size_t)net*R_TOT + row0 + rr)*CC + c] = s;
    }
}

// ---------------------------------------------------------------------------
// K_B: fused prefix + output fill (unchanged — proven).
// ---------------------------------------------------------------------------
__global__ __launch_bounds__(512)
void final_kernel(const float* __restrict__ s0w, const float* __restrict__ s1w,
                  const float* __restrict__ uni, float* __restrict__ out)
{
    const int bi = blockIdx.x;        // b*S + i
    const int b = bi >> 7, i = bi & (SS-1);
    const int tid = threadIdx.x;
    const int lane = tid & 63;
    const int k    = tid & 127;
    const int wv2  = (tid >> 6) & 1;
    const int slot = tid >> 7;

    __shared__ float E[SS*CC];
    __shared__ float Qe[SS*CC];
    __shared__ float red[4][4][2];
    __shared__ float mnL[CC], sh1L[CC], uniL[CC];

    if (tid < CC) {
        sh1L[tid] = s1w[(size_t)bi*CC + tid];
        uniL[tid] = uni[tid];
    }

    const float* __restrict__ sm0b = s0w + (size_t)(2*R_TOT + b*SS)*CC;
    const float* __restrict__ sm1b = s1w + (size_t)(2*R_TOT + b*SS)*CC;

    for (int pass = 0; pass < 4; ++pass) {
        const int c = pass*4 + slot;
        float x0 = 0.f, x1 = 0.f, e = 0.f, q = 0.f;
        if (c < CC) {
            x0 = sm0b[(size_t)k*CC + c];
            x1 = sm1b[(size_t)k*CC + c];
            float m = x0;
            #pragma unroll
            for (int off = 32; off >= 1; off >>= 1) m = fmaxf(m, __shfl_xor(m, off));
            float ss = x1;
            #pragma unroll
            for (int off = 32; off >= 1; off >>= 1) ss += __shfl_xor(ss, off);
            if (lane == 0) { red[0][slot][wv2] = m; red[1][slot][wv2] = ss; }
        }
        __syncthreads();
        if (c < CC) {
            const float M = fmaxf(red[0][slot][0], red[0][slot][1]);
            e = __expf(x0 - M);
            q = e * x1;
            #pragma unroll
            for (int off = 1; off <= 32; off <<= 1) {
                const float te = __shfl_up(e, off);
                const float tq = __shfl_up(q, off);
                if (lane >= off) { e += te; q += tq; }
            }
            if (lane == 63) { red[2][slot][wv2] = e; red[3][slot][wv2] = q; }
        }
        __syncthreads();
        if (c < CC) {
            if (wv2 == 1) { e += red[2][slot][0]; q += red[3][slot][0]; }
            E [k*CC + c] = e;
            Qe[k*CC + c] = q;
            if (k == 0) mnL[c] = (red[1][slot][0] + red[1][slot][1]) * (1.f/SS);
        }
        __syncthreads();
    }

    const float* __restrict__ st1 = s1w + (size_t)(R_TOT + b*SS)*CC;
    float* __restrict__ o = out + (size_t)bi*SS*CC;
    if (tid < 448) {
        const int e0 = tid * 4;
        float v[4];
        #pragma unroll
        for (int u = 0; u < 4; ++u) {
            const int idx = e0 + u;
            const int j = idx / CC, c = idx - j*CC;
            float add;
            if (i <= j) {
                const float Ei = (i > 0) ? E [(i-1)*CC + c] : 0.f;
                const float Qi = (i > 0) ? Qe[(i-1)*CC + c] : 0.f;
                add = (Qe[j*CC + c] - Qi) / (E[j*CC + c] - Ei);
            } else {
                add = mnL[c];
            }
            v[u] = sh1L[c] + st1[idx] + uniL[c] + add;
        }
        *(float4*)&o[e0] = make_float4(v[0], v[1], v[2], v[3]);
    }
}

extern "C" void kernel_launch(void* const* d_in, const int* in_sizes, int n_in,
                              void* d_out, int out_size, void* d_ws, size_t ws_size,
                              hipStream_t stream)
{
    const float* mem = (const float*)d_in[0];
    AllP P;
    for (int n = 0; n < 3; ++n) {
        const int base = 1 + 8*n;
        P.n[n].W1  = (const float*)d_in[base+0];
        P.n[n].b1  = (const float*)d_in[base+1];
        P.n[n].W2  = (const float*)d_in[base+2];
        P.n[n].b2  = (const float*)d_in[base+3];
        P.n[n].s0W = (const float*)d_in[base+4];
        P.n[n].s0b = (const float*)d_in[base+5];
        P.n[n].s1W = (const float*)d_in[base+6];
        P.n[n].s1b = (const float*)d_in[base+7];
    }
    const float* uni = (const float*)d_in[25];
    float* ws  = (float*)d_ws;
    float* s0  = ws + S0_OFF;
    float* s1  = ws + S1_OFF;
    unsigned short* w1b = (unsigned short*)((char*)d_ws + W1B_OFF_BYTES);
    unsigned short* w2b = (unsigned short*)((char*)d_ws + W2B_OFF_BYTES);
    float* out = (float*)d_out;

    hipLaunchKernelGGL(cvt_kernel,   dim3(480),   dim3(512), 0, stream, P, w1b, w2b);
    hipLaunchKernelGGL(mlp_fused,    dim3(192),   dim3(512), 0, stream, mem, P, w1b, w2b, s0, s1);
    hipLaunchKernelGGL(final_kernel, dim3(BB*SS), dim3(512), 0, stream, s0, s1, uni, out);
}